// Round 9
// baseline (3088.711 us; speedup 1.0000x reference)
//
#include <hip/hip_runtime.h>
#include <hip/hip_bf16.h>
#include <stdint.h>

// out = relu(x @ W_up^T) @ W_down^T + x @ W_expert
// (softmax-of-top-k weights sum to 1 -> MoE gating is a mathematical no-op)
//
// 256x256-tile bf16 MFMA GEMM, BK=64, 512 threads (8 waves 2Mx4N), 16x16x32
// MFMA (proven 0-conflict fragment pattern). SINGLE-buffer LDS (64 KiB) ->
// 2 blocks/CU resident; cross-block TLP absorbs the per-tile stage drain
// (m97 mechanism). Schedule per tile: compute -> lgkm0+bar -> stage(t+1) ->
// vmcnt(0)+bar. B fragments persist in regs (24 ds_read_b128/wave/tile).
// XOR-swizzled LDS (linear global_load_lds dest + pre-swizzled source +
// swizzled ds_read).

#define DIM 2048
#define MTOT 16384

typedef unsigned short u16;
typedef __bf16 bf16x8 __attribute__((ext_vector_type(8)));
typedef float f32x4 __attribute__((ext_vector_type(4)));

__device__ __forceinline__ u16 f2bf(float f) {
    union { float f; unsigned int u; } a; a.f = f;
    unsigned int u = a.u;
    unsigned int r = (u + 0x7fffu + ((u >> 16) & 1u)) >> 16;  // RNE
    return (u16)r;
}

__device__ __forceinline__ bf16x8 frag_load(const void* p) {
    union { uint4 u; bf16x8 b; } x;
    x.u = *(const uint4*)p;
    return x.b;
}

// ---------------------------------------------------------------------------
// Merged fp32->bf16 conversions (x, W_up, W_down) in one grid-strided kernel.
__global__ void cvt_all(const float* __restrict__ x, const float* __restrict__ Wu,
                        const float* __restrict__ Wd, u16* __restrict__ Abig,
                        u16* __restrict__ Wup, u16* __restrict__ Bbig) {
    const long NX = (long)MTOT * DIM / 4;   // 8388608 float4 items
    const long NW = (long)DIM * DIM / 4;    // 1048576
    long i = (long)blockIdx.x * blockDim.x + threadIdx.x;
    long stride = (long)gridDim.x * blockDim.x;
    for (; i < NX + 2 * NW; i += stride) {
        const float* src; u16* dst; int dld, doff; long e;
        if (i < NX)            { src = x;  dst = Abig; dld = 4096; doff = 2048; e = i << 2; }
        else if (i < NX + NW)  { src = Wu; dst = Wup;  dld = 2048; doff = 0;    e = (i - NX) << 2; }
        else                   { src = Wd; dst = Bbig; dld = 4096; doff = 0;    e = (i - NX - NW) << 2; }
        long row = e >> 11;
        int col = (int)(e & 2047);
        float4 v = *(const float4*)(src + e);
        union { u16 q[4]; uint2 d; } u;
        u.q[0] = f2bf(v.x); u.q[1] = f2bf(v.y);
        u.q[2] = f2bf(v.z); u.q[3] = f2bf(v.w);
        *(uint2*)(dst + row * (long)dld + doff + col) = u.d;
    }
}

// W_expert is [K,N] applied as x @ W_expert; need B^T layout [N,K] into B_big
// columns 2048..4095.
__global__ void cvt_transpose(const float* __restrict__ W, u16* __restrict__ dst) {
    __shared__ float t[32][33];
    int bx = blockIdx.x & 63;
    int by = blockIdx.x >> 6;
    int x = threadIdx.x & 31, y = threadIdx.x >> 5;
    #pragma unroll
    for (int j = 0; j < 32; j += 8)
        t[y + j][x] = W[(size_t)(by * 32 + y + j) * 2048 + bx * 32 + x];
    __syncthreads();
    #pragma unroll
    for (int j = 0; j < 32; j += 8)
        dst[(size_t)(bx * 32 + y + j) * 4096 + 2048 + by * 32 + x] = f2bf(t[x][y + j]);
}

// ---------------------------------------------------------------------------
// 256^2 GEMM: C[M,N] = A[M,K] @ B[N,K]^T, 16x16x32 MFMA.
// LDS (single buffer, 64 KiB): A halves (2 x 128rows x 128B) at 0,
// B halves at 32768. Swizzle: (r,c) at byte r*128 + ((2c) ^ ((r&7)<<4)).
template <int MODE>
__global__ __launch_bounds__(512, 4)
void gemm256(const u16* __restrict__ A, const u16* __restrict__ B,
             void* __restrict__ Cptr, int lda, int ldb, int K) {
    __shared__ char lds[65536];

    const int tid  = threadIdx.x;
    const int lane = tid & 63;
    const int wv   = tid >> 6;   // 0..7
    const int wr   = wv >> 2;    // 0..1  (row 64-block within each 128-half)
    const int wc   = wv & 3;     // 0..3  (col 32-strip within each 128-half)

    // XCD-aware bijective swizzle (grid=512, divisible by 8)
    int bid = blockIdx.x;
    int cpx = gridDim.x >> 3;
    int swz = (bid & 7) * cpx + (bid >> 3);
    int tile_n = swz & 7;        // N/256 = 8
    int tile_m = swz >> 3;       // M/256 = 64

    const int rowA0 = tile_m * 256;
    const int rowB0 = tile_n * 256;

    // Staging: per half 2 loads/thread. Load j: linear LDS byte j*8192+tid*16
    // -> row r = j*64 + (tid>>3), linear col (tid&7)*16. Pre-swizzled source:
    const int r_sub = tid >> 3;
    const int c_src = ((tid & 7) ^ (r_sub & 7)) << 3;  // element offset
    const u16* pAb = A + (size_t)(rowA0 + r_sub) * lda + c_src;
    const u16* pBb = B + (size_t)(rowB0 + r_sub) * ldb + c_src;

    f32x4 acc[2][2][4][2];
    #pragma unroll
    for (int a = 0; a < 2; ++a)
        #pragma unroll
        for (int b = 0; b < 2; ++b)
            #pragma unroll
            for (int m = 0; m < 4; ++m)
                #pragma unroll
                for (int n = 0; n < 2; ++n)
                    acc[a][b][m][n] = (f32x4){0.f, 0.f, 0.f, 0.f};

    bf16x8 av[4][2];    // current A half's fragments (4 m x 2 kk)
    bf16x8 bva[2][2];   // B half 0 fragments, live all tile
    bf16x8 bvb[2][2];   // B half 1 fragments, live all tile
    const int kA = (lane >> 4) << 4;   // byte base of k-part, kk=0

#define STAGE_A(H, KOFF) do {                                                   \
    const u16* _s = pAb + (size_t)((H) * 128) * lda + (KOFF);                   \
    __builtin_amdgcn_global_load_lds(                                           \
        (const __attribute__((address_space(1))) void*)_s,                      \
        (__attribute__((address_space(3))) void*)(lds + (H)*16384 + (wv<<10)),  \
        16, 0, 0);                                                              \
    __builtin_amdgcn_global_load_lds(                                           \
        (const __attribute__((address_space(1))) void*)(_s + (size_t)64 * lda), \
        (__attribute__((address_space(3))) void*)(lds + (H)*16384 + 8192 + (wv<<10)), \
        16, 0, 0);                                                              \
  } while (0)

#define STAGE_B(H, KOFF) do {                                                   \
    const u16* _s = pBb + (size_t)((H) * 128) * ldb + (KOFF);                   \
    __builtin_amdgcn_global_load_lds(                                           \
        (const __attribute__((address_space(1))) void*)_s,                      \
        (__attribute__((address_space(3))) void*)(lds + 32768 + (H)*16384 + (wv<<10)), \
        16, 0, 0);                                                              \
    __builtin_amdgcn_global_load_lds(                                           \
        (const __attribute__((address_space(1))) void*)(_s + (size_t)64 * ldb), \
        (__attribute__((address_space(3))) void*)(lds + 32768 + (H)*16384 + 8192 + (wv<<10)), \
        16, 0, 0);                                                              \
  } while (0)

#define DSREAD_A(MH) do {                                                       \
    _Pragma("unroll")                                                           \
    for (int m = 0; m < 4; ++m) {                                               \
        int ra = (wr << 6) + (m << 4) + (lane & 15);                            \
        const char* _b = (const char*)lds + (MH)*16384 + (ra << 7);             \
        int sw = (ra & 7) << 4;                                                 \
        av[m][0] = frag_load(_b + (kA ^ sw));                                   \
        av[m][1] = frag_load(_b + ((64 + kA) ^ sw));                            \
    } } while (0)

#define DSREAD_B(NH, DST) do {                                                  \
    _Pragma("unroll")                                                           \
    for (int n = 0; n < 2; ++n) {                                               \
        int rb = (wc << 5) + (n << 4) + (lane & 15);                            \
        const char* _b = (const char*)lds + 32768 + (NH)*16384 + (rb << 7);     \
        int sw = (rb & 7) << 4;                                                 \
        DST[n][0] = frag_load(_b + (kA ^ sw));                                  \
        DST[n][1] = frag_load(_b + ((64 + kA) ^ sw));                           \
    } } while (0)

#define MFMA_Q(MH, NH, BV) do {                                                 \
    __builtin_amdgcn_s_setprio(1);                                              \
    _Pragma("unroll")                                                           \
    for (int m = 0; m < 4; ++m)                                                 \
        _Pragma("unroll")                                                       \
        for (int n = 0; n < 2; ++n) {                                           \
            acc[MH][NH][m][n] = __builtin_amdgcn_mfma_f32_16x16x32_bf16(        \
                av[m][0], BV[n][0], acc[MH][NH][m][n], 0, 0, 0);                \
            acc[MH][NH][m][n] = __builtin_amdgcn_mfma_f32_16x16x32_bf16(        \
                av[m][1], BV[n][1], acc[MH][NH][m][n], 0, 0, 0);                \
        }                                                                       \
    __builtin_amdgcn_s_setprio(0);                                              \
  } while (0)

#define WAIT_VM0() asm volatile("s_waitcnt vmcnt(0)" ::: "memory")
#define WAIT_LGKM0() asm volatile("s_waitcnt lgkmcnt(0)" ::: "memory")
#define BAR() __builtin_amdgcn_s_barrier()

    // Prologue: stage tile 0, full drain.
    STAGE_A(0, 0);
    STAGE_B(0, 0);
    STAGE_B(1, 0);
    STAGE_A(1, 0);
    WAIT_VM0();
    BAR();

    const int nK = K >> 6;
    for (int t = 0; t < nK; ++t) {
        // Compute tile t (single buffer).
        DSREAD_B(0, bva);
        DSREAD_B(1, bvb);
        DSREAD_A(0);
        MFMA_Q(0, 0, bva);
        MFMA_Q(0, 1, bvb);
        DSREAD_A(1);
        MFMA_Q(1, 1, bvb);
        MFMA_Q(1, 0, bva);
        // All reads retired before anyone overwrites the buffer.
        WAIT_LGKM0();
        BAR();
        if (t + 1 < nK) {
            const int koff = (t + 1) << 6;
            STAGE_A(0, koff);
            STAGE_B(0, koff);
            STAGE_B(1, koff);
            STAGE_A(1, koff);
            WAIT_VM0();   // stage landed (drain covered by co-resident block)
            BAR();
        }
    }

    // Epilogue. 16x16 C/D layout: col = lane&15, row = (lane>>4)*4 + reg.
    #pragma unroll
    for (int mh = 0; mh < 2; ++mh)
        #pragma unroll
        for (int m = 0; m < 4; ++m)
            #pragma unroll
            for (int r = 0; r < 4; ++r) {
                int row = rowA0 + mh * 128 + (wr << 6) + (m << 4) + ((lane >> 4) << 2) + r;
                #pragma unroll
                for (int nh = 0; nh < 2; ++nh)
                    #pragma unroll
                    for (int n = 0; n < 2; ++n) {
                        int col = tile_n * 256 + nh * 128 + (wc << 5) + (n << 4) + (lane & 15);
                        float v = acc[mh][nh][m][n][r];
                        if (MODE == 0) {
                            ((u16*)Cptr)[(size_t)row * 4096 + col] = f2bf(fmaxf(v, 0.f));
                        } else {
                            ((float*)Cptr)[(size_t)row * 2048 + col] = v;
                        }
                    }
            }
#undef STAGE_A
#undef STAGE_B
#undef DSREAD_A
#undef DSREAD_B
#undef MFMA_Q
#undef WAIT_VM0
#undef WAIT_LGKM0
#undef BAR
}

// ---------------------------------------------------------------------------
extern "C" void kernel_launch(void* const* d_in, const int* in_sizes, int n_in,
                              void* d_out, int out_size, void* d_ws, size_t ws_size,
                              hipStream_t stream) {
    const float* x        = (const float*)d_in[0];
    const float* W_up     = (const float*)d_in[1];
    const float* W_down   = (const float*)d_in[2];
    // d_in[3] = W_gate: unused (softmax over top-k sums to 1 -> gating no-op)
    const float* W_expert = (const float*)d_in[4];

    // Workspace (bf16 as u16):
    //   A_big [16384][4096]: cols 0..2047 = h (GEMM1 output), 2048..4095 = x
    //   B_big [2048][4096] : cols 0..2047 = W_down, 2048..4095 = W_expert^T
    //   W_up_bf [2048][2048]
    u16* Abig = (u16*)d_ws;
    u16* Bbig = Abig + (size_t)MTOT * 4096;
    u16* Wup  = Bbig + (size_t)DIM * 4096;

    cvt_all<<<2048, 256, 0, stream>>>(x, W_up, W_down, Abig, Wup, Bbig);
    cvt_transpose<<<4096, 256, 0, stream>>>(W_expert, Bbig);

    // GEMM1: h = relu(x @ W_up^T) -> bf16 into A_big left half
    gemm256<0><<<512, 512, 0, stream>>>(Abig + 2048, Wup, Abig, 4096, 2048, 2048);
    // GEMM2: out = A_big @ B_big^T = h @ W_down^T + x @ W_expert (fp32)
    gemm256<1><<<512, 512, 0, stream>>>(Abig, Bbig, d_out, 4096, 4096, 4096);
}

// Round 10
// 488.508 us; speedup vs baseline: 6.3227x; 6.3227x over previous
//
#include <hip/hip_runtime.h>
#include <hip/hip_bf16.h>
#include <stdint.h>

// out = relu(x @ W_up^T) @ W_down^T + x @ W_expert
// (softmax-of-top-k weights sum to 1 -> MoE gating is a mathematical no-op)
//
// 256x256-tile bf16 MFMA GEMM, BK=64, 512 threads (8 waves 2Mx4N), 16x16x32
// MFMA (proven 0-conflict fragment pattern). SINGLE-buffer LDS (64 KiB) ->
// 2 blocks/CU resident; cross-block TLP absorbs the per-tile stage drain
// (m97 mechanism). Schedule per tile: compute -> lgkm0+bar -> stage(t+1) ->
// vmcnt(0)+bar. B fragments persist in regs (24 ds_read_b128/wave/tile).
// XOR-swizzled LDS (linear global_load_lds dest + pre-swizzled source +
// swizzled ds_read).
//
// r9 post-mortem: __launch_bounds__(512,4) capped VGPR at 64 -> scratch spill
// (FETCH_SIZE 196MB -> 3.6GB). (512,2) restores the 116-VGPR allocation;
// occupancy is then LDS/VGPR-determined = 2 blocks/CU (16 waves).

#define DIM 2048
#define MTOT 16384

typedef unsigned short u16;
typedef __bf16 bf16x8 __attribute__((ext_vector_type(8)));
typedef float f32x4 __attribute__((ext_vector_type(4)));

__device__ __forceinline__ u16 f2bf(float f) {
    union { float f; unsigned int u; } a; a.f = f;
    unsigned int u = a.u;
    unsigned int r = (u + 0x7fffu + ((u >> 16) & 1u)) >> 16;  // RNE
    return (u16)r;
}

__device__ __forceinline__ bf16x8 frag_load(const void* p) {
    union { uint4 u; bf16x8 b; } x;
    x.u = *(const uint4*)p;
    return x.b;
}

// ---------------------------------------------------------------------------
// Merged fp32->bf16 conversions (x, W_up, W_down) in one grid-strided kernel.
__global__ void cvt_all(const float* __restrict__ x, const float* __restrict__ Wu,
                        const float* __restrict__ Wd, u16* __restrict__ Abig,
                        u16* __restrict__ Wup, u16* __restrict__ Bbig) {
    const long NX = (long)MTOT * DIM / 4;   // 8388608 float4 items
    const long NW = (long)DIM * DIM / 4;    // 1048576
    long i = (long)blockIdx.x * blockDim.x + threadIdx.x;
    long stride = (long)gridDim.x * blockDim.x;
    for (; i < NX + 2 * NW; i += stride) {
        const float* src; u16* dst; int dld, doff; long e;
        if (i < NX)            { src = x;  dst = Abig; dld = 4096; doff = 2048; e = i << 2; }
        else if (i < NX + NW)  { src = Wu; dst = Wup;  dld = 2048; doff = 0;    e = (i - NX) << 2; }
        else                   { src = Wd; dst = Bbig; dld = 4096; doff = 0;    e = (i - NX - NW) << 2; }
        long row = e >> 11;
        int col = (int)(e & 2047);
        float4 v = *(const float4*)(src + e);
        union { u16 q[4]; uint2 d; } u;
        u.q[0] = f2bf(v.x); u.q[1] = f2bf(v.y);
        u.q[2] = f2bf(v.z); u.q[3] = f2bf(v.w);
        *(uint2*)(dst + row * (long)dld + doff + col) = u.d;
    }
}

// W_expert is [K,N] applied as x @ W_expert; need B^T layout [N,K] into B_big
// columns 2048..4095.
__global__ void cvt_transpose(const float* __restrict__ W, u16* __restrict__ dst) {
    __shared__ float t[32][33];
    int bx = blockIdx.x & 63;
    int by = blockIdx.x >> 6;
    int x = threadIdx.x & 31, y = threadIdx.x >> 5;
    #pragma unroll
    for (int j = 0; j < 32; j += 8)
        t[y + j][x] = W[(size_t)(by * 32 + y + j) * 2048 + bx * 32 + x];
    __syncthreads();
    #pragma unroll
    for (int j = 0; j < 32; j += 8)
        dst[(size_t)(bx * 32 + y + j) * 4096 + 2048 + by * 32 + x] = f2bf(t[x][y + j]);
}

// ---------------------------------------------------------------------------
// 256^2 GEMM: C[M,N] = A[M,K] @ B[N,K]^T, 16x16x32 MFMA.
// LDS (single buffer, 64 KiB): A halves (2 x 128rows x 128B) at 0,
// B halves at 32768. Swizzle: (r,c) at byte r*128 + ((2c) ^ ((r&7)<<4)).
template <int MODE>
__global__ __launch_bounds__(512, 2)
void gemm256(const u16* __restrict__ A, const u16* __restrict__ B,
             void* __restrict__ Cptr, int lda, int ldb, int K) {
    __shared__ char lds[65536];

    const int tid  = threadIdx.x;
    const int lane = tid & 63;
    const int wv   = tid >> 6;   // 0..7
    const int wr   = wv >> 2;    // 0..1  (row 64-block within each 128-half)
    const int wc   = wv & 3;     // 0..3  (col 32-strip within each 128-half)

    // XCD-aware bijective swizzle (grid=512, divisible by 8)
    int bid = blockIdx.x;
    int cpx = gridDim.x >> 3;
    int swz = (bid & 7) * cpx + (bid >> 3);
    int tile_n = swz & 7;        // N/256 = 8
    int tile_m = swz >> 3;       // M/256 = 64

    const int rowA0 = tile_m * 256;
    const int rowB0 = tile_n * 256;

    // Staging: per half 2 loads/thread. Load j: linear LDS byte j*8192+tid*16
    // -> row r = j*64 + (tid>>3), linear col (tid&7)*16. Pre-swizzled source:
    const int r_sub = tid >> 3;
    const int c_src = ((tid & 7) ^ (r_sub & 7)) << 3;  // element offset
    const u16* pAb = A + (size_t)(rowA0 + r_sub) * lda + c_src;
    const u16* pBb = B + (size_t)(rowB0 + r_sub) * ldb + c_src;

    f32x4 acc[2][2][4][2];
    #pragma unroll
    for (int a = 0; a < 2; ++a)
        #pragma unroll
        for (int b = 0; b < 2; ++b)
            #pragma unroll
            for (int m = 0; m < 4; ++m)
                #pragma unroll
                for (int n = 0; n < 2; ++n)
                    acc[a][b][m][n] = (f32x4){0.f, 0.f, 0.f, 0.f};

    bf16x8 av[4][2];    // current A half's fragments (4 m x 2 kk)
    bf16x8 bva[2][2];   // B half 0 fragments, live all tile
    bf16x8 bvb[2][2];   // B half 1 fragments, live all tile
    const int kA = (lane >> 4) << 4;   // byte base of k-part, kk=0

#define STAGE_A(H, KOFF) do {                                                   \
    const u16* _s = pAb + (size_t)((H) * 128) * lda + (KOFF);                   \
    __builtin_amdgcn_global_load_lds(                                           \
        (const __attribute__((address_space(1))) void*)_s,                      \
        (__attribute__((address_space(3))) void*)(lds + (H)*16384 + (wv<<10)),  \
        16, 0, 0);                                                              \
    __builtin_amdgcn_global_load_lds(                                           \
        (const __attribute__((address_space(1))) void*)(_s + (size_t)64 * lda), \
        (__attribute__((address_space(3))) void*)(lds + (H)*16384 + 8192 + (wv<<10)), \
        16, 0, 0);                                                              \
  } while (0)

#define STAGE_B(H, KOFF) do {                                                   \
    const u16* _s = pBb + (size_t)((H) * 128) * ldb + (KOFF);                   \
    __builtin_amdgcn_global_load_lds(                                           \
        (const __attribute__((address_space(1))) void*)_s,                      \
        (__attribute__((address_space(3))) void*)(lds + 32768 + (H)*16384 + (wv<<10)), \
        16, 0, 0);                                                              \
    __builtin_amdgcn_global_load_lds(                                           \
        (const __attribute__((address_space(1))) void*)(_s + (size_t)64 * ldb), \
        (__attribute__((address_space(3))) void*)(lds + 32768 + (H)*16384 + 8192 + (wv<<10)), \
        16, 0, 0);                                                              \
  } while (0)

#define DSREAD_A(MH) do {                                                       \
    _Pragma("unroll")                                                           \
    for (int m = 0; m < 4; ++m) {                                               \
        int ra = (wr << 6) + (m << 4) + (lane & 15);                            \
        const char* _b = (const char*)lds + (MH)*16384 + (ra << 7);             \
        int sw = (ra & 7) << 4;                                                 \
        av[m][0] = frag_load(_b + (kA ^ sw));                                   \
        av[m][1] = frag_load(_b + ((64 + kA) ^ sw));                            \
    } } while (0)

#define DSREAD_B(NH, DST) do {                                                  \
    _Pragma("unroll")                                                           \
    for (int n = 0; n < 2; ++n) {                                               \
        int rb = (wc << 5) + (n << 4) + (lane & 15);                            \
        const char* _b = (const char*)lds + 32768 + (NH)*16384 + (rb << 7);     \
        int sw = (rb & 7) << 4;                                                 \
        DST[n][0] = frag_load(_b + (kA ^ sw));                                  \
        DST[n][1] = frag_load(_b + ((64 + kA) ^ sw));                           \
    } } while (0)

#define MFMA_Q(MH, NH, BV) do {                                                 \
    __builtin_amdgcn_s_setprio(1);                                              \
    _Pragma("unroll")                                                           \
    for (int m = 0; m < 4; ++m)                                                 \
        _Pragma("unroll")                                                       \
        for (int n = 0; n < 2; ++n) {                                           \
            acc[MH][NH][m][n] = __builtin_amdgcn_mfma_f32_16x16x32_bf16(        \
                av[m][0], BV[n][0], acc[MH][NH][m][n], 0, 0, 0);                \
            acc[MH][NH][m][n] = __builtin_amdgcn_mfma_f32_16x16x32_bf16(        \
                av[m][1], BV[n][1], acc[MH][NH][m][n], 0, 0, 0);                \
        }                                                                       \
    __builtin_amdgcn_s_setprio(0);                                              \
  } while (0)

#define WAIT_VM0() asm volatile("s_waitcnt vmcnt(0)" ::: "memory")
#define WAIT_LGKM0() asm volatile("s_waitcnt lgkmcnt(0)" ::: "memory")
#define BAR() __builtin_amdgcn_s_barrier()

    // Prologue: stage tile 0, full drain.
    STAGE_A(0, 0);
    STAGE_B(0, 0);
    STAGE_B(1, 0);
    STAGE_A(1, 0);
    WAIT_VM0();
    BAR();

    const int nK = K >> 6;
    for (int t = 0; t < nK; ++t) {
        // Compute tile t (single buffer).
        DSREAD_B(0, bva);
        DSREAD_B(1, bvb);
        DSREAD_A(0);
        MFMA_Q(0, 0, bva);
        MFMA_Q(0, 1, bvb);
        DSREAD_A(1);
        MFMA_Q(1, 1, bvb);
        MFMA_Q(1, 0, bva);
        // All reads retired before anyone overwrites the buffer.
        WAIT_LGKM0();
        BAR();
        if (t + 1 < nK) {
            const int koff = (t + 1) << 6;
            STAGE_A(0, koff);
            STAGE_B(0, koff);
            STAGE_B(1, koff);
            STAGE_A(1, koff);
            WAIT_VM0();   // stage landed (drain covered by co-resident block)
            BAR();
        }
    }

    // Epilogue. 16x16 C/D layout: col = lane&15, row = (lane>>4)*4 + reg.
    #pragma unroll
    for (int mh = 0; mh < 2; ++mh)
        #pragma unroll
        for (int m = 0; m < 4; ++m)
            #pragma unroll
            for (int r = 0; r < 4; ++r) {
                int row = rowA0 + mh * 128 + (wr << 6) + (m << 4) + ((lane >> 4) << 2) + r;
                #pragma unroll
                for (int nh = 0; nh < 2; ++nh)
                    #pragma unroll
                    for (int n = 0; n < 2; ++n) {
                        int col = tile_n * 256 + nh * 128 + (wc << 5) + (n << 4) + (lane & 15);
                        float v = acc[mh][nh][m][n][r];
                        if (MODE == 0) {
                            ((u16*)Cptr)[(size_t)row * 4096 + col] = f2bf(fmaxf(v, 0.f));
                        } else {
                            ((float*)Cptr)[(size_t)row * 2048 + col] = v;
                        }
                    }
            }
#undef STAGE_A
#undef STAGE_B
#undef DSREAD_A
#undef DSREAD_B
#undef MFMA_Q
#undef WAIT_VM0
#undef WAIT_LGKM0
#undef BAR
}

// ---------------------------------------------------------------------------
extern "C" void kernel_launch(void* const* d_in, const int* in_sizes, int n_in,
                              void* d_out, int out_size, void* d_ws, size_t ws_size,
                              hipStream_t stream) {
    const float* x        = (const float*)d_in[0];
    const float* W_up     = (const float*)d_in[1];
    const float* W_down   = (const float*)d_in[2];
    // d_in[3] = W_gate: unused (softmax over top-k sums to 1 -> gating no-op)
    const float* W_expert = (const float*)d_in[4];

    // Workspace (bf16 as u16):
    //   A_big [16384][4096]: cols 0..2047 = h (GEMM1 output), 2048..4095 = x
    //   B_big [2048][4096] : cols 0..2047 = W_down, 2048..4095 = W_expert^T
    //   W_up_bf [2048][2048]
    u16* Abig = (u16*)d_ws;
    u16* Bbig = Abig + (size_t)MTOT * 4096;
    u16* Wup  = Bbig + (size_t)DIM * 4096;

    cvt_all<<<2048, 256, 0, stream>>>(x, W_up, W_down, Abig, Wup, Bbig);
    cvt_transpose<<<4096, 256, 0, stream>>>(W_expert, Bbig);

    // GEMM1: h = relu(x @ W_up^T) -> bf16 into A_big left half
    gemm256<0><<<512, 512, 0, stream>>>(Abig + 2048, Wup, Abig, 4096, 2048, 2048);
    // GEMM2: out = A_big @ B_big^T = h @ W_down^T + x @ W_expert (fp32)
    gemm256<1><<<512, 512, 0, stream>>>(Abig, Bbig, d_out, 4096, 4096, 4096);
}

// Round 11
// 372.515 us; speedup vs baseline: 8.2915x; 1.3114x over previous
//
#include <hip/hip_runtime.h>
#include <hip/hip_bf16.h>
#include <stdint.h>

// out = relu(x @ W_up^T) @ W_down^T + x @ W_expert
// (softmax-of-top-k weights sum to 1 -> MoE gating is a mathematical no-op)
//
// CHAMPION CONFIG (r3): 256x256-tile bf16 MFMA GEMM, BK=64, 512 threads
// (8 waves 2Mx4N), 16x16x32 MFMA (proven 0-conflict fragment pattern).
// 2-sync-per-K-tile schedule: two fused regions per tile
// {ds_reads + stage-next + MFMA cluster} with deep-aged counted vmcnt
// (vmcnt(4) mid, vmcnt(2) end — awaited loads aged >= half tile ~1700cy)
// + raw s_barrier at the two region boundaries only. B fragments persist
// in registers for the whole K-tile -> 24 ds_read_b128/wave/tile.
// XOR-swizzled LDS (linear global_load_lds dest + pre-swizzled source +
// swizzled ds_read) -> 0 bank conflicts.
//
// Structural notes from r4-r10 exploration (all regressions vs this):
//  - 32x32x16 frag pattern: 2.5e7 bank conflicts (r4)
//  - 1-sync full-drain schedules: 282/308 us (r5/r10)
//  - 4-phase fine interleave: 251/237 us (r6/r7)
//  - B-direct-from-global: 333 us (r8)
//  - occupancy: acc=128 AGPR + 116 VGPR = 244/wave -> 2 waves/SIMD, 1 block/CU
//    (second block impossible; launch_bounds(512,4) just forces spill, r9)

#define DIM 2048
#define MTOT 16384

typedef unsigned short u16;
typedef __bf16 bf16x8 __attribute__((ext_vector_type(8)));
typedef float f32x4 __attribute__((ext_vector_type(4)));

__device__ __forceinline__ u16 f2bf(float f) {
    union { float f; unsigned int u; } a; a.f = f;
    unsigned int u = a.u;
    unsigned int r = (u + 0x7fffu + ((u >> 16) & 1u)) >> 16;  // RNE
    return (u16)r;
}

__device__ __forceinline__ bf16x8 frag_load(const void* p) {
    union { uint4 u; bf16x8 b; } x;
    x.u = *(const uint4*)p;
    return x.b;
}

// ---------------------------------------------------------------------------
// Merged fp32->bf16 conversions (x, W_up, W_down) in one grid-strided kernel.
__global__ void cvt_all(const float* __restrict__ x, const float* __restrict__ Wu,
                        const float* __restrict__ Wd, u16* __restrict__ Abig,
                        u16* __restrict__ Wup, u16* __restrict__ Bbig) {
    const long NX = (long)MTOT * DIM / 4;   // 8388608 float4 items
    const long NW = (long)DIM * DIM / 4;    // 1048576
    long i = (long)blockIdx.x * blockDim.x + threadIdx.x;
    long stride = (long)gridDim.x * blockDim.x;
    for (; i < NX + 2 * NW; i += stride) {
        const float* src; u16* dst; int dld, doff; long e;
        if (i < NX)            { src = x;  dst = Abig; dld = 4096; doff = 2048; e = i << 2; }
        else if (i < NX + NW)  { src = Wu; dst = Wup;  dld = 2048; doff = 0;    e = (i - NX) << 2; }
        else                   { src = Wd; dst = Bbig; dld = 4096; doff = 0;    e = (i - NX - NW) << 2; }
        long row = e >> 11;
        int col = (int)(e & 2047);
        float4 v = *(const float4*)(src + e);
        union { u16 q[4]; uint2 d; } u;
        u.q[0] = f2bf(v.x); u.q[1] = f2bf(v.y);
        u.q[2] = f2bf(v.z); u.q[3] = f2bf(v.w);
        *(uint2*)(dst + row * (long)dld + doff + col) = u.d;
    }
}

// W_expert is [K,N] applied as x @ W_expert; need B^T layout [N,K] into B_big
// columns 2048..4095.
__global__ void cvt_transpose(const float* __restrict__ W, u16* __restrict__ dst) {
    __shared__ float t[32][33];
    int bx = blockIdx.x & 63;
    int by = blockIdx.x >> 6;
    int x = threadIdx.x & 31, y = threadIdx.x >> 5;
    #pragma unroll
    for (int j = 0; j < 32; j += 8)
        t[y + j][x] = W[(size_t)(by * 32 + y + j) * 2048 + bx * 32 + x];
    __syncthreads();
    #pragma unroll
    for (int j = 0; j < 32; j += 8)
        dst[(size_t)(bx * 32 + y + j) * 4096 + 2048 + by * 32 + x] = f2bf(t[x][y + j]);
}

// ---------------------------------------------------------------------------
// 256^2 GEMM: C[M,N] = A[M,K] @ B[N,K]^T, 16x16x32 MFMA.
// LDS per buffer: A halves (2 x 128rows x 128B) at 0, B halves at 32768.
// Two buffers -> 128 KiB. Swizzle: (r,c) at byte r*128 + ((2c) ^ ((r&7)<<4)).
// Stage order per tile: A0, B0 (region 1), B1, A1 (region 2).
// Sync invariant: entering tile t, exactly t's A1 (2 loads) is in flight.
//   mid-sync:  in-flight = {A1^t, A0^{t+1}, B0^{t+1}} = 6 -> vmcnt(4) retires A1^t
//   end-sync:  in-flight = 8 (t+1 halves)             -> vmcnt(2) retires A0,B0,B1
template <int MODE>
__global__ __launch_bounds__(512, 2)
void gemm256(const u16* __restrict__ A, const u16* __restrict__ B,
             void* __restrict__ Cptr, int lda, int ldb, int K) {
    __shared__ char lds[2][65536];

    const int tid  = threadIdx.x;
    const int lane = tid & 63;
    const int wv   = tid >> 6;   // 0..7
    const int wr   = wv >> 2;    // 0..1  (row 64-block within each 128-half)
    const int wc   = wv & 3;     // 0..3  (col 32-strip within each 128-half)

    // XCD-aware bijective swizzle (grid=512, divisible by 8)
    int bid = blockIdx.x;
    int cpx = gridDim.x >> 3;
    int swz = (bid & 7) * cpx + (bid >> 3);
    int tile_n = swz & 7;        // N/256 = 8
    int tile_m = swz >> 3;       // M/256 = 64

    const int rowA0 = tile_m * 256;
    const int rowB0 = tile_n * 256;

    // Staging: per half 2 loads/thread. Load j: linear LDS byte j*8192+tid*16
    // -> row r = j*64 + (tid>>3), linear col (tid&7)*16. Pre-swizzled source:
    const int r_sub = tid >> 3;
    const int c_src = ((tid & 7) ^ (r_sub & 7)) << 3;  // element offset
    const u16* pAb = A + (size_t)(rowA0 + r_sub) * lda + c_src;
    const u16* pBb = B + (size_t)(rowB0 + r_sub) * ldb + c_src;

    f32x4 acc[2][2][4][2];
    #pragma unroll
    for (int a = 0; a < 2; ++a)
        #pragma unroll
        for (int b = 0; b < 2; ++b)
            #pragma unroll
            for (int m = 0; m < 4; ++m)
                #pragma unroll
                for (int n = 0; n < 2; ++n)
                    acc[a][b][m][n] = (f32x4){0.f, 0.f, 0.f, 0.f};

    bf16x8 av[4][2];    // current A half's fragments (4 m x 2 kk)
    bf16x8 bva[2][2];   // B half 0 fragments, live all tile
    bf16x8 bvb[2][2];   // B half 1 fragments, live all tile
    const int kA = (lane >> 4) << 4;   // byte base of k-part, kk=0

#define STAGE_A(H, KOFF, BUF) do {                                              \
    const u16* _s = pAb + (size_t)((H) * 128) * lda + (KOFF);                   \
    __builtin_amdgcn_global_load_lds(                                           \
        (const __attribute__((address_space(1))) void*)_s,                      \
        (__attribute__((address_space(3))) void*)((char*)lds[BUF] + (H)*16384 + (wv<<10)), \
        16, 0, 0);                                                              \
    __builtin_amdgcn_global_load_lds(                                           \
        (const __attribute__((address_space(1))) void*)(_s + (size_t)64 * lda), \
        (__attribute__((address_space(3))) void*)((char*)lds[BUF] + (H)*16384 + 8192 + (wv<<10)), \
        16, 0, 0);                                                              \
  } while (0)

#define STAGE_B(H, KOFF, BUF) do {                                              \
    const u16* _s = pBb + (size_t)((H) * 128) * ldb + (KOFF);                   \
    __builtin_amdgcn_global_load_lds(                                           \
        (const __attribute__((address_space(1))) void*)_s,                      \
        (__attribute__((address_space(3))) void*)((char*)lds[BUF] + 32768 + (H)*16384 + (wv<<10)), \
        16, 0, 0);                                                              \
    __builtin_amdgcn_global_load_lds(                                           \
        (const __attribute__((address_space(1))) void*)(_s + (size_t)64 * ldb), \
        (__attribute__((address_space(3))) void*)((char*)lds[BUF] + 32768 + (H)*16384 + 8192 + (wv<<10)), \
        16, 0, 0);                                                              \
  } while (0)

#define DSREAD_A(MH, CUR) do {                                                  \
    _Pragma("unroll")                                                           \
    for (int m = 0; m < 4; ++m) {                                               \
        int ra = (wr << 6) + (m << 4) + (lane & 15);                            \
        const char* _b = (const char*)lds[CUR] + (MH)*16384 + (ra << 7);        \
        int sw = (ra & 7) << 4;                                                 \
        av[m][0] = frag_load(_b + (kA ^ sw));                                   \
        av[m][1] = frag_load(_b + ((64 + kA) ^ sw));                            \
    } } while (0)

#define DSREAD_B(NH, CUR, DST) do {                                             \
    _Pragma("unroll")                                                           \
    for (int n = 0; n < 2; ++n) {                                               \
        int rb = (wc << 5) + (n << 4) + (lane & 15);                            \
        const char* _b = (const char*)lds[CUR] + 32768 + (NH)*16384 + (rb << 7);\
        int sw = (rb & 7) << 4;                                                 \
        DST[n][0] = frag_load(_b + (kA ^ sw));                                  \
        DST[n][1] = frag_load(_b + ((64 + kA) ^ sw));                           \
    } } while (0)

#define MFMA_Q(MH, NH, BV) do {                                                 \
    __builtin_amdgcn_s_setprio(1);                                              \
    _Pragma("unroll")                                                           \
    for (int m = 0; m < 4; ++m)                                                 \
        _Pragma("unroll")                                                       \
        for (int n = 0; n < 2; ++n) {                                           \
            acc[MH][NH][m][n] = __builtin_amdgcn_mfma_f32_16x16x32_bf16(        \
                av[m][0], BV[n][0], acc[MH][NH][m][n], 0, 0, 0);                \
            acc[MH][NH][m][n] = __builtin_amdgcn_mfma_f32_16x16x32_bf16(        \
                av[m][1], BV[n][1], acc[MH][NH][m][n], 0, 0, 0);                \
        }                                                                       \
    __builtin_amdgcn_s_setprio(0);                                              \
  } while (0)

#define WAIT_VM(N) asm volatile("s_waitcnt vmcnt(" #N ")" ::: "memory")
#define WAIT_LGKM0() asm volatile("s_waitcnt lgkmcnt(0)" ::: "memory")
#define BAR() __builtin_amdgcn_s_barrier()

    // Prologue: stage tile 0 in order A0,B0,B1,A1; guarantee all but A1.
    STAGE_A(0, 0, 0);
    STAGE_B(0, 0, 0);
    STAGE_B(1, 0, 0);
    STAGE_A(1, 0, 0);
    WAIT_VM(2);
    BAR();

    const int nK = K >> 6;
    int cur = 0;
    for (int t = 0; t < nK - 1; ++t) {
        const int koff = (t + 1) << 6;
        const int nxt = cur ^ 1;
        // ---- Region 1: Q00, Q01 (A0 x {B0,B1}) ----
        DSREAD_B(0, cur, bva);
        DSREAD_B(1, cur, bvb);
        DSREAD_A(0, cur);
        STAGE_A(0, koff, nxt);
        STAGE_B(0, koff, nxt);
        MFMA_Q(0, 0, bva);
        MFMA_Q(0, 1, bvb);
        // mid-sync: retire A1^t (in-flight = 6 -> vmcnt(4))
        WAIT_LGKM0();
        WAIT_VM(4);
        BAR();
        // ---- Region 2: Q11, Q10 (A1 x {B1,B0}) ----
        DSREAD_A(1, cur);
        STAGE_B(1, koff, nxt);
        STAGE_A(1, koff, nxt);
        MFMA_Q(1, 1, bvb);
        MFMA_Q(1, 0, bva);
        // end-sync: retire A0,B0,B1 of t+1 (in-flight = 8 -> vmcnt(2))
        WAIT_LGKM0();
        WAIT_VM(2);
        BAR();
        cur = nxt;
    }

    // Last tile (no prefetch). Entering: only this tile's A1 in flight.
    DSREAD_B(0, cur, bva);
    DSREAD_B(1, cur, bvb);
    DSREAD_A(0, cur);
    MFMA_Q(0, 0, bva);
    MFMA_Q(0, 1, bvb);
    WAIT_LGKM0();
    WAIT_VM(0);
    BAR();
    DSREAD_A(1, cur);
    MFMA_Q(1, 1, bvb);
    MFMA_Q(1, 0, bva);

    // Epilogue. 16x16 C/D layout: col = lane&15, row = (lane>>4)*4 + reg.
    #pragma unroll
    for (int mh = 0; mh < 2; ++mh)
        #pragma unroll
        for (int m = 0; m < 4; ++m)
            #pragma unroll
            for (int r = 0; r < 4; ++r) {
                int row = rowA0 + mh * 128 + (wr << 6) + (m << 4) + ((lane >> 4) << 2) + r;
                #pragma unroll
                for (int nh = 0; nh < 2; ++nh)
                    #pragma unroll
                    for (int n = 0; n < 2; ++n) {
                        int col = tile_n * 256 + nh * 128 + (wc << 5) + (n << 4) + (lane & 15);
                        float v = acc[mh][nh][m][n][r];
                        if (MODE == 0) {
                            ((u16*)Cptr)[(size_t)row * 4096 + col] = f2bf(fmaxf(v, 0.f));
                        } else {
                            ((float*)Cptr)[(size_t)row * 2048 + col] = v;
                        }
                    }
            }
#undef STAGE_A
#undef STAGE_B
#undef DSREAD_A
#undef DSREAD_B
#undef MFMA_Q
#undef WAIT_VM
#undef WAIT_LGKM0
#undef BAR
}

// ---------------------------------------------------------------------------
extern "C" void kernel_launch(void* const* d_in, const int* in_sizes, int n_in,
                              void* d_out, int out_size, void* d_ws, size_t ws_size,
                              hipStream_t stream) {
    const float* x        = (const float*)d_in[0];
    const float* W_up     = (const float*)d_in[1];
    const float* W_down   = (const float*)d_in[2];
    // d_in[3] = W_gate: unused (softmax over top-k sums to 1 -> gating no-op)
    const float* W_expert = (const float*)d_in[4];

    // Workspace (bf16 as u16):
    //   A_big [16384][4096]: cols 0..2047 = h (GEMM1 output), 2048..4095 = x
    //   B_big [2048][4096] : cols 0..2047 = W_down, 2048..4095 = W_expert^T
    //   W_up_bf [2048][2048]
    u16* Abig = (u16*)d_ws;
    u16* Bbig = Abig + (size_t)MTOT * 4096;
    u16* Wup  = Bbig + (size_t)DIM * 4096;

    cvt_all<<<2048, 256, 0, stream>>>(x, W_up, W_down, Abig, Wup, Bbig);
    cvt_transpose<<<4096, 256, 0, stream>>>(W_expert, Bbig);

    // GEMM1: h = relu(x @ W_up^T) -> bf16 into A_big left half
    gemm256<0><<<512, 512, 0, stream>>>(Abig + 2048, Wup, Abig, 4096, 2048, 2048);
    // GEMM2: out = A_big @ B_big^T = h @ W_down^T + x @ W_expert (fp32)
    gemm256<1><<<512, 512, 0, stream>>>(Abig, Bbig, d_out, 4096, 4096, 4096);
}